// Round 9
// baseline (159.161 us; speedup 1.0000x reference)
//
#include <hip/hip_runtime.h>
#include <hip/hip_bf16.h>
#include <math.h>

#define NNODES 131072
#define BW 16   // nodes per (single-wave) block

typedef __attribute__((ext_vector_type(8))) short bf16x8;
typedef __attribute__((ext_vector_type(4))) float f32x4;

// bf16 weights (prep): W_h [128*64] @0 | W_s [128*256] @8192 | W_g [64*128] @40960
__device__ short g_w[49152];
// bf16 fused weight Wc[o][v] = sum_h W_V[o][h]*W_h[h][v], [64*64] row-major
__device__ short g_wc[4096];

__device__ __forceinline__ short f2b(float f) {
  union { float f; unsigned u; } x; x.f = f;
  unsigned r = x.u + 0x7fffu + ((x.u >> 16) & 1u);
  return (short)(r >> 16);
}
__device__ __forceinline__ short c2b(float f) {
  __hip_bfloat16 h = __float2bfloat16(f);
  return *reinterpret_cast<short*>(&h);
}

__global__ void prep_kernel(const float* __restrict__ W_h, const float* __restrict__ W_V,
                            const float* __restrict__ W_s_w, const float* __restrict__ W_g_w) {
  int b = blockIdx.x;
  if (b < 48) {
    int i4 = (b * 256 + threadIdx.x) * 4;
    const float* src;
    if (i4 < 8192)       src = W_h   + i4;
    else if (i4 < 40960) src = W_s_w + (i4 - 8192);
    else                 src = W_g_w + (i4 - 40960);
    float4 q = *(const float4*)src;
    short4 p;
    p.x = f2b(q.x); p.y = f2b(q.y); p.z = f2b(q.z); p.w = f2b(q.w);
    *(short4*)(g_w + i4) = p;
  } else {
    int gid = (b - 48) * 256 + threadIdx.x;   // 0..1023
    int o  = gid >> 4;
    int v0 = (gid & 15) * 4;
    float a0 = 0.f, a1 = 0.f, a2 = 0.f, a3 = 0.f;
    #pragma unroll 8
    for (int h = 0; h < 128; ++h) {
      float wv = W_V[o * 128 + h];
      float4 wh = *(const float4*)(W_h + h * 64 + v0);
      a0 += wv * wh.x; a1 += wv * wh.y; a2 += wv * wh.z; a3 += wv * wh.w;
    }
    short4 p;
    p.x = f2b(a0); p.y = f2b(a1); p.z = f2b(a2); p.w = f2b(a3);
    *(short4*)(g_wc + o * 64 + v0) = p;
  }
}

// One wave = one block = 16 nodes. No inter-wave coupling, barriers are 1-wave (free).
// LDS 12288 B/block -> ~12-13 blocks/CU, each an independent instruction stream.
//   NORM @0    [16 rows][256B] bf16, byte ^= (nl&15)<<4
//   SOUT @4096 [16 rows][256B] bf16, same swizzle
//   VST  @0    [16 rows][768B] f32,  byte ^= (nl&15)<<4  (overlays NORM+SOUT at the end)
// V/s MFMA A-frags load DIRECTLY from global (lane (l15,g) owns node l15, k-offset g*8):
// zero staging LDS, zero redundancy (each input byte read by exactly one lane).

__global__ __launch_bounds__(64, 3)
void gvp_kernel(const float* __restrict__ s_in, const float* __restrict__ V_in,
                const float* __restrict__ W_s_b, const float* __restrict__ W_g_b,
                float* __restrict__ s_out_g, float* __restrict__ V_out_g)
{
  __shared__ __align__(16) char smem[12288];
  char* const NORM = smem;
  char* const SOUT = smem + 4096;
  char* const VSTb = smem;

  const short* const g_wh = g_w;
  const short* const g_ws = g_w + 8192;
  const short* const g_wg = g_w + 40960;

  const int lane = threadIdx.x;     // 0..63
  const int l15  = lane & 15;
  const int g    = lane >> 4;       // 0..3
  const int k8   = g << 3;          // A/B frag k-offset
  const long n0  = (long)blockIdx.x * BW;

  // ---- V A-frags direct from global: af[c][ks], rows c*16+l15, k = ks*32+k8+j ----
  bf16x8 af[3][2];
  #pragma unroll
  for (int ks = 0; ks < 2; ++ks) {
    const float* vp = V_in + (n0 + l15) * 192 + (ks * 32 + k8) * 3;  // 96B contiguous
    float b[24];
    #pragma unroll
    for (int i = 0; i < 6; ++i) *(float4*)(b + 4 * i) = *(const float4*)(vp + 4 * i);
    #pragma unroll
    for (int c = 0; c < 3; ++c) {
      bf16x8 p;
      #pragma unroll
      for (int j = 0; j < 8; ++j) p[j] = c2b(b[3 * j + c]);
      af[c][ks] = p;
    }
  }
  // ---- s A-frags direct from global: a3s[ks], rows l15, k = ks*32+k8+j ----
  bf16x8 a3s[4];
  #pragma unroll
  for (int ks = 0; ks < 4; ++ks) {
    const float* sp = s_in + (n0 + l15) * 128 + ks * 32 + k8;        // 32B contiguous
    float4 q0 = *(const float4*)sp;
    float4 q1 = *(const float4*)(sp + 4);
    bf16x8 p;
    p[0] = c2b(q0.x); p[1] = c2b(q0.y); p[2] = c2b(q0.z); p[3] = c2b(q0.w);
    p[4] = c2b(q1.x); p[5] = c2b(q1.y); p[6] = c2b(q1.z); p[7] = c2b(q1.w);
    a3s[ks] = p;
  }

  // ---- GEMM1 (Vh, 48x128 K=64) in two h-halves; norms straight to NORM LDS ----
  #pragma unroll
  for (int half = 0; half < 2; ++half) {
    f32x4 acc[3][4];
    #pragma unroll
    for (int c = 0; c < 3; ++c)
      #pragma unroll
      for (int hh = 0; hh < 4; ++hh) { f32x4 z = {0.f,0.f,0.f,0.f}; acc[c][hh] = z; }
    bf16x8 bh[4][2];
    #pragma unroll
    for (int hh = 0; hh < 4; ++hh)
      #pragma unroll
      for (int ks = 0; ks < 2; ++ks)
        bh[hh][ks] = *(const bf16x8*)(g_wh + ((half * 4 + hh) * 16 + l15) * 64 + ks * 32 + k8);
    #pragma unroll
    for (int c = 0; c < 3; ++c)
      #pragma unroll
      for (int hh = 0; hh < 4; ++hh) {
        acc[c][hh] = __builtin_amdgcn_mfma_f32_16x16x32_bf16(af[c][0], bh[hh][0], acc[c][hh], 0, 0, 0);
        acc[c][hh] = __builtin_amdgcn_mfma_f32_16x16x32_bf16(af[c][1], bh[hh][1], acc[c][hh], 0, 0, 0);
      }
    #pragma unroll
    for (int hh = 0; hh < 4; ++hh)
      #pragma unroll
      for (int i = 0; i < 4; ++i) {
        int nl = g * 4 + i;
        int h  = (half * 4 + hh) * 16 + l15;
        float x0 = acc[0][hh][i], x1 = acc[1][hh][i], x2 = acc[2][hh][i];
        float nrm = sqrtf(x0 * x0 + x1 * x1 + x2 * x2);
        *(short*)(NORM + nl * 256 + (((unsigned)(h * 2)) ^ ((unsigned)((nl & 15) << 4)))) = c2b(nrm);
      }
  }
  __syncthreads();  // 1-wave: ~free; orders NORM writes before reads

  // ---- GEMM3: s_out[16][128] = relu([s|norm]·W_s^T + b), K=256 ----
  f32x4 acc3[8];
  #pragma unroll
  for (int oo = 0; oo < 8; ++oo) { f32x4 z = {0.f,0.f,0.f,0.f}; acc3[oo] = z; }
  #pragma unroll
  for (int ks = 0; ks < 8; ++ks) {
    bf16x8 a;
    if (ks < 4) {
      a = a3s[ks];
    } else {
      int ko = (ks - 4) * 32 + k8;
      a = *(const bf16x8*)(NORM + l15 * 256 + (((unsigned)(ko * 2)) ^ ((unsigned)((l15 & 15) << 4))));
    }
    #pragma unroll
    for (int oo = 0; oo < 8; ++oo) {
      bf16x8 b = *(const bf16x8*)(g_ws + (oo * 16 + l15) * 256 + ks * 32 + k8);
      acc3[oo] = __builtin_amdgcn_mfma_f32_16x16x32_bf16(a, b, acc3[oo], 0, 0, 0);
    }
  }
  // epilogue: global stores (oo-adjacent completes 128B lines) + SOUT stage
  {
    float bias[8];
    #pragma unroll
    for (int oo = 0; oo < 8; ++oo) bias[oo] = W_s_b[oo * 16 + l15];
    #pragma unroll
    for (int i = 0; i < 4; ++i) {
      int nl = g * 4 + i;
      long rowb = (n0 + nl) * 128;
      unsigned sw = (unsigned)((nl & 15) << 4);
      #pragma unroll
      for (int oo = 0; oo < 8; ++oo) {
        float v = fmaxf(acc3[oo][i] + bias[oo], 0.0f);
        s_out_g[rowb + oo * 16 + l15] = v;
        *(short*)(SOUT + nl * 256 + (((unsigned)((oo * 16 + l15) * 2)) ^ sw)) = c2b(v);
      }
    }
  }
  __syncthreads();  // orders SOUT writes before reads

  // ---- GEMM4: gate logits, 16x64 K=128 ----
  f32x4 acc4[4];
  #pragma unroll
  for (int oo = 0; oo < 4; ++oo) { f32x4 z = {0.f,0.f,0.f,0.f}; acc4[oo] = z; }
  #pragma unroll
  for (int ks = 0; ks < 4; ++ks) {
    int ko = ks * 32 + k8;
    bf16x8 a = *(const bf16x8*)(SOUT + l15 * 256 + (((unsigned)(ko * 2)) ^ ((unsigned)((l15 & 15) << 4))));
    #pragma unroll
    for (int oo = 0; oo < 4; ++oo) {
      bf16x8 b = *(const bf16x8*)(g_wg + (oo * 16 + l15) * 128 + ko);
      acc4[oo] = __builtin_amdgcn_mfma_f32_16x16x32_bf16(a, b, acc4[oo], 0, 0, 0);
    }
  }

  // ---- GEMM2 (deferred): V_out_pre via fused Wc on the still-live af frags ----
  f32x4 acc2[3][4];
  #pragma unroll
  for (int c = 0; c < 3; ++c)
    #pragma unroll
    for (int oo = 0; oo < 4; ++oo) { f32x4 z = {0.f,0.f,0.f,0.f}; acc2[c][oo] = z; }
  {
    bf16x8 bc[4][2];
    #pragma unroll
    for (int oo = 0; oo < 4; ++oo)
      #pragma unroll
      for (int ks = 0; ks < 2; ++ks)
        bc[oo][ks] = *(const bf16x8*)(g_wc + (oo * 16 + l15) * 64 + ks * 32 + k8);
    #pragma unroll
    for (int c = 0; c < 3; ++c)
      #pragma unroll
      for (int oo = 0; oo < 4; ++oo) {
        acc2[c][oo] = __builtin_amdgcn_mfma_f32_16x16x32_bf16(af[c][0], bc[oo][0], acc2[c][oo], 0, 0, 0);
        acc2[c][oo] = __builtin_amdgcn_mfma_f32_16x16x32_bf16(af[c][1], bc[oo][1], acc2[c][oo], 0, 0, 0);
      }
  }

  // ---- gate (lane-aligned with acc2) -> VST f32, swizzled ----
  {
    float bg[4];
    #pragma unroll
    for (int oo = 0; oo < 4; ++oo) bg[oo] = W_g_b[oo * 16 + l15];
    #pragma unroll
    for (int oo = 0; oo < 4; ++oo)
      #pragma unroll
      for (int i = 0; i < 4; ++i) {
        int nl = g * 4 + i;
        float sg = 1.0f / (1.0f + __expf(-(acc4[oo][i] + bg[oo])));
        int o = oo * 16 + l15;
        unsigned sw = (unsigned)((nl & 15) << 4);
        unsigned base = (unsigned)(nl * 768);
        *(float*)(VSTb + base + (((unsigned)((o * 3 + 0) * 4)) ^ sw)) = acc2[0][oo][i] * sg;
        *(float*)(VSTb + base + (((unsigned)((o * 3 + 1) * 4)) ^ sw)) = acc2[1][oo][i] * sg;
        *(float*)(VSTb + base + (((unsigned)((o * 3 + 2) * 4)) ^ sw)) = acc2[2][oo][i] * sg;
      }
  }
  __syncthreads();  // orders VST writes (overlay) after NORM/SOUT reads, before reads

  // ---- coalesced full-line V_out store: float4 x 64 lanes = 1KB/instr ----
  {
    float4* Vo = (float4*)(V_out_g + n0 * 192);
    #pragma unroll
    for (int j = 0; j < 12; ++j) {
      int f   = j * 64 + lane;              // flat float4 index, 0..767
      int nl  = (f * 1366) >> 16;           // f / 48 (exact for f < 768)
      int rem = f - nl * 48;
      float4 q = *(const float4*)(VSTb + nl * 768 +
                   (((unsigned)(rem * 16)) ^ ((unsigned)((nl & 15) << 4))));
      Vo[f] = q;
    }
  }
}

extern "C" void kernel_launch(void* const* d_in, const int* in_sizes, int n_in,
                              void* d_out, int out_size, void* d_ws, size_t ws_size,
                              hipStream_t stream) {
  const float* s_in  = (const float*)d_in[0];
  const float* V_in  = (const float*)d_in[1];
  const float* W_h   = (const float*)d_in[2];
  const float* W_V   = (const float*)d_in[3];
  const float* W_s_w = (const float*)d_in[4];
  const float* W_s_b = (const float*)d_in[5];
  const float* W_g_w = (const float*)d_in[6];
  const float* W_g_b = (const float*)d_in[7];
  float* out = (float*)d_out;
  float* s_out_g = out;
  float* V_out_g = out + (size_t)NNODES * 128;
  hipLaunchKernelGGL(prep_kernel, dim3(52), dim3(256), 0, stream,
                     W_h, W_V, W_s_w, W_g_w);
  hipLaunchKernelGGL(gvp_kernel, dim3(NNODES / BW), dim3(64), 0, stream,
                     s_in, V_in, W_s_b, W_g_b, s_out_g, V_out_g);
}